// Round 8
// baseline (6988.071 us; speedup 1.0000x reference)
//
#include <hip/hip_runtime.h>
#include <hip/hip_fp16.h>

typedef _Float16 half8 __attribute__((ext_vector_type(8)));
typedef _Float16 half4_t __attribute__((ext_vector_type(4)));
typedef float    float4_ __attribute__((ext_vector_type(4)));

#define TSTEPS 512
#define NA 64
#define NB 128
#define NC 8
#define FSTRIDE 32                // ints per flag slot = 128 B (own cache line)

// workspace layout (bytes)
#define FLA_OFF   0               // 64 flags  x 128 B
#define FLB_OFF   8192            // 128 flags x 128 B
#define FLC_OFF   24576           // 8 flags   x 128 B
#define H1_OFF    32768
#define H1_PHASE  262144          // 1024 cols x 128 batch x 2B, fragment-major
#define H2_OFF    (H1_OFF + 2 * H1_PHASE)
#define X_OFF     (H2_OFF + 2 * H1_PHASE)
#define X_TSTRIDE 16384           // 64 cols x 128 batch x 2B per step
#define ZERO_BYTES X_OFF          // flags + H1 + H2 zeroed each call

__device__ __forceinline__ float sigf(float x) { return 1.0f / (1.0f + __expf(-x)); }

__device__ __forceinline__ half8 zero8() {
    half8 z;
#pragma unroll
    for (int j = 0; j < 8; ++j) z[j] = (_Float16)0.0f;
    return z;
}

__device__ __forceinline__ half8 wfrag_load(const float* Wa, int lda,
                                            const float* Wb, int ldb,
                                            int split, int row, int k0) {
    const float* s = (k0 < split) ? (Wa + (size_t)row * lda + k0)
                                  : (Wb + (size_t)row * ldb + (k0 - split));
    float4_ lo = *(const float4_*)s;
    float4_ hi = *(const float4_*)(s + 4);
    half8 r;
    r[0] = (_Float16)lo[0]; r[1] = (_Float16)lo[1];
    r[2] = (_Float16)lo[2]; r[3] = (_Float16)lo[3];
    r[4] = (_Float16)hi[0]; r[5] = (_Float16)hi[1];
    r[6] = (_Float16)hi[2]; r[7] = (_Float16)hi[3];
    return r;
}

// ---- coherence-point access primitives (NO fences, NO buffer_inv/wbl2) ----

// 16B device-scope-coherent plain load (sc1: reads the coherence point, never
// hits a stale per-XCD L2 line; coalesces like a normal load). Compiler does
// NOT track waitcnt for asm loads — consumer passes values through the VMW*
// fences below before use. All loads/waits are volatile asm => program order
// is preserved, so the vmcnt bookkeeping below is exact.
__device__ __forceinline__ half8 ldg_sc1_16(const void* p) {
    half8 r;
    asm volatile("global_load_dwordx4 %0, %1, off sc1" : "=v"(r) : "v"(p));
    return r;
}

// partial waits tying a 16-fragment group (B) — oldest group complete
#define VMW16(N, A) asm volatile("s_waitcnt vmcnt(" #N ")" : \
    "+v"((A)[0]), "+v"((A)[1]), "+v"((A)[2]), "+v"((A)[3]), "+v"((A)[4]), \
    "+v"((A)[5]), "+v"((A)[6]), "+v"((A)[7]), "+v"((A)[8]), "+v"((A)[9]), \
    "+v"((A)[10]), "+v"((A)[11]), "+v"((A)[12]), "+v"((A)[13]), \
    "+v"((A)[14]), "+v"((A)[15]) :: "memory")
// partial waits tying a 9-fragment group (A)
#define VMW9(N, A) asm volatile("s_waitcnt vmcnt(" #N ")" : \
    "+v"((A)[0]), "+v"((A)[1]), "+v"((A)[2]), "+v"((A)[3]), "+v"((A)[4]), \
    "+v"((A)[5]), "+v"((A)[6]), "+v"((A)[7]), "+v"((A)[8]) :: "memory")
// full drain tying an 8-fragment group (C)
#define VMWAIT8(A) asm volatile("s_waitcnt vmcnt(0)" : \
    "+v"((A)[0]), "+v"((A)[1]), "+v"((A)[2]), "+v"((A)[3]), \
    "+v"((A)[4]), "+v"((A)[5]), "+v"((A)[6]), "+v"((A)[7]) :: "memory")

// 2B write-through store (sc0 sc1): lands at the coherence point, acked by vmcnt.
__device__ __forceinline__ void stg_coh_h(void* p, float v) {
    union { _Float16 h; unsigned short s; } u;
    u.h = (_Float16)v;
    unsigned int d = u.s;
    asm volatile("global_store_short %0, %1, off sc0 sc1" :: "v"(p), "v"(d) : "memory");
}

__device__ __forceinline__ void stg_coh_int(void* p, int v) {
    asm volatile("global_store_dword %0, %1, off sc0 sc1" :: "v"(p), "v"(v) : "memory");
}

// producer-side ordering: my write-through stores acked (vmcnt 0), then block
// barrier, then (thread 0) flag store. No cache maintenance involved.
__device__ __forceinline__ void publish(int* fbase, int idx, int v) {
    asm volatile("s_waitcnt vmcnt(0)" ::: "memory");
    __syncthreads();
    if (threadIdx.x == 0) stg_coh_int(fbase + idx * FSTRIDE, v);
}

// ---- de-contended flag waits: flags on private lines, ONE polling wave ----

__device__ __forceinline__ int ld_flag(const int* f, int idx) {
    return __hip_atomic_load(f + idx * FSTRIDE, __ATOMIC_RELAXED,
                             __HIP_MEMORY_SCOPE_AGENT);
}

// A-group: need all fA >= t (h1[t-1] ready) and all fB >= t-1 (phase free)
__device__ __forceinline__ void waitA(const int* fA, const int* fB, int t) {
    if (threadIdx.x < 64) {
        const int lane = threadIdx.x;
        for (;;) {
            int a  = ld_flag(fA, lane);
            int b0 = ld_flag(fB, lane);
            int b1 = ld_flag(fB, 64 + lane);
            if (__all((a >= t) && (b0 >= t - 1) && (b1 >= t - 1))) break;
            __builtin_amdgcn_s_sleep(1);
        }
    }
    __syncthreads();
}

// B-group: fA >= t+1 (h1[t]), fB >= t (h2[t-1]), fC >= t-1 (phase free)
__device__ __forceinline__ void waitB(const int* fA, const int* fB, const int* fC, int t) {
    if (threadIdx.x < 64) {
        const int lane = threadIdx.x;
        for (;;) {
            int a  = ld_flag(fA, lane);
            int b0 = ld_flag(fB, lane);
            int b1 = ld_flag(fB, 64 + lane);
            int c  = ld_flag(fC, lane & 7);
            if (__all((a >= t + 1) && (b0 >= t) && (b1 >= t) && (c >= t - 1))) break;
            __builtin_amdgcn_s_sleep(1);
        }
    }
    __syncthreads();
}

// C-group: fB >= t+1 (h2[t] ready)
__device__ __forceinline__ void waitC(const int* fB, int t) {
    if (threadIdx.x < 64) {
        const int lane = threadIdx.x;
        for (;;) {
            int b0 = ld_flag(fB, lane);
            int b1 = ld_flag(fB, 64 + lane);
            if (__all((b0 >= t + 1) && (b1 >= t + 1))) break;
            __builtin_amdgcn_s_sleep(1);
        }
    }
    __syncthreads();
}

// Convert input [128 b][512 t][64 i] fp32 -> fragment-major fp16 X[t][kt][quad][b][j]
extern "C" __global__ void prep_x(const float* __restrict__ in, char* __restrict__ ws) {
    const int t = blockIdx.x;
    char* X = ws + X_OFF + (size_t)t * X_TSTRIDE;
    for (int idx = threadIdx.x; idx < 8192; idx += 256) {
        int kt = idx >> 12, rem = idx & 4095;
        int quad = rem >> 10, rem2 = rem & 1023;
        int b = rem2 >> 3, j = rem2 & 7;
        int i = kt * 32 + quad * 8 + j;
        float v = in[(size_t)b * 32768 + (size_t)t * 64 + i];
        *(_Float16*)(X + (size_t)idx * 2) = (_Float16)v;
    }
}

extern "C" __global__ __launch_bounds__(256, 1)
void lstm_persistent(const float* __restrict__ Wih1, const float* __restrict__ Whh1,
                     const float* __restrict__ bih1, const float* __restrict__ bhh1,
                     const float* __restrict__ Wih2, const float* __restrict__ Whh2,
                     const float* __restrict__ bih2, const float* __restrict__ bhh2,
                     const float* __restrict__ Wout, const float* __restrict__ bout,
                     char* __restrict__ ws, float* __restrict__ out) {
    const int tid = threadIdx.x;
    const int w = tid >> 6, lane = tid & 63;
    const int quad = lane >> 4, cl = lane & 15;
    const int laneoff = quad * 2048 + cl * 16;
    int* fA = (int*)(ws + FLA_OFF);
    int* fB = (int*)(ws + FLB_OFF);
    int* fC = (int*)(ws + FLC_OFF);
    char* H1 = ws + H1_OFF;
    char* H2 = ws + H2_OFF;
    char* X  = ws + X_OFF;
    const int blk = blockIdx.x;
    __shared__ float redbuf[8192];

    if (blk < NA) {
        // ---------- layer-1: h1 cols [c0,c0+16), K = 1088 (34 k-tiles), waves split K
        const int c0 = blk * 16;
        const int kbase = w * 9;
        half8 wfr[4][9];
#pragma unroll
        for (int nt = 0; nt < 4; ++nt) {
            int row = nt * 1024 + c0 + cl;
#pragma unroll
            for (int kk = 0; kk < 9; ++kk) {
                int ktg = kbase + kk;
                if (ktg < 34) wfr[nt][kk] = wfrag_load(Wih1, 64, Whh1, 1024, 64, row, ktg * 32 + quad * 8);
                else          wfr[nt][kk] = zero8();
            }
        }
        float ba[4];
#pragma unroll
        for (int g = 0; g < 4; ++g) ba[g] = bih1[g * 1024 + c0 + cl] + bhh1[g * 1024 + c0 + cl];
        float cst[2][4];
#pragma unroll
        for (int mi = 0; mi < 2; ++mi)
#pragma unroll
            for (int r = 0; r < 4; ++r) cst[mi][r] = 0.0f;
        const int cc = c0 + cl;
        const int woffbase = (cc >> 5) * 8192 + ((cc >> 3) & 3) * 2048 + (cc & 7) * 2;

        for (int t = 0; t < TSTEPS; ++t) {
            waitA(fA, fB, t);

            const char* xb  = X + (size_t)t * X_TSTRIDE;
            const char* h1r = H1 + (((t & 1) ^ 1) ? H1_PHASE : 0);
            char*       h1w = H1 + ((t & 1) ? H1_PHASE : 0);
            const char* kb[9];
#pragma unroll
            for (int kk = 0; kk < 9; ++kk) {
                int ktg = kbase + kk; if (ktg > 33) ktg = 33;
                kb[kk] = (ktg < 2) ? (xb + ktg * 8192) : (h1r + (ktg - 2) * 8192);
            }
            float4_ acc[8][4];
#pragma unroll
            for (int mt = 0; mt < 8; ++mt)
#pragma unroll
                for (int nt = 0; nt < 4; ++nt) acc[mt][nt] = (float4_){0.f, 0.f, 0.f, 0.f};
            // depth-3 fragment ring, partial vmcnt waits:
            // at iter mt: issued = 27 + 9*min(mt,5); needed = 9*(mt+1)
            // wait N = issued-needed: mt<=5 -> 18, mt==6 -> 9, mt==7 -> 0
            half8 af[3][9];
#pragma unroll
            for (int p = 0; p < 3; ++p)
#pragma unroll
                for (int kk = 0; kk < 9; ++kk)
                    af[p][kk] = ldg_sc1_16(kb[kk] + laneoff + p * 256);
#pragma unroll
            for (int mt = 0; mt < 8; ++mt) {
                const int s = mt % 3;
                if (mt < 6)       { VMW9(18, af[s]); }
                else if (mt == 6) { VMW9(9,  af[s]); }
                else              { VMW9(0,  af[s]); }
#pragma unroll
                for (int kk = 0; kk < 9; ++kk)
#pragma unroll
                    for (int nt = 0; nt < 4; ++nt)
                        acc[mt][nt] = __builtin_amdgcn_mfma_f32_16x16x32_f16(
                            af[s][kk], wfr[nt][kk], acc[mt][nt], 0, 0, 0);
                if (mt < 5) {
#pragma unroll
                    for (int kk = 0; kk < 9; ++kk)
                        af[s][kk] = ldg_sc1_16(kb[kk] + laneoff + (mt + 3) * 256);
                }
            }
#pragma unroll
            for (int r = 0; r < 4; ++r) {
                if (w != r) {
#pragma unroll
                    for (int mi = 0; mi < 2; ++mi)
#pragma unroll
                        for (int nt = 0; nt < 4; ++nt)
                            *(float4_*)&redbuf[(((w * 2 + mi) * 4 + nt) * 64 + lane) * 4] = acc[2 * r + mi][nt];
                }
                __syncthreads();
                if (w == r) {
#pragma unroll
                    for (int wo = 0; wo < 4; ++wo) if (wo != r) {
#pragma unroll
                        for (int mi = 0; mi < 2; ++mi)
#pragma unroll
                            for (int nt = 0; nt < 4; ++nt)
                                acc[2 * r + mi][nt] += *(const float4_*)&redbuf[(((wo * 2 + mi) * 4 + nt) * 64 + lane) * 4];
                    }
                }
                __syncthreads();
            }
            float4_ mine[2][4];
#pragma unroll
            for (int r = 0; r < 4; ++r) if (w == r) {
#pragma unroll
                for (int mi = 0; mi < 2; ++mi)
#pragma unroll
                    for (int nt = 0; nt < 4; ++nt) mine[mi][nt] = acc[2 * r + mi][nt];
            }
#pragma unroll
            for (int mi = 0; mi < 2; ++mi) {
#pragma unroll
                for (int r = 0; r < 4; ++r) {
                    float iv = mine[mi][0][r] + ba[0];
                    float fv = mine[mi][1][r] + ba[1];
                    float gv = mine[mi][2][r] + ba[2];
                    float ov = mine[mi][3][r] + ba[3];
                    float c = sigf(fv) * cst[mi][r] + sigf(iv) * tanhf(gv);
                    float h = sigf(ov) * tanhf(c);
                    cst[mi][r] = c;
                    int m = (2 * w + mi) * 16 + quad * 4 + r;
                    stg_coh_h(h1w + woffbase + m * 16, h);
                }
            }
            publish(fA, blk, t + 1);
        }
    } else if (blk < NA + NB) {
        // ---------- layer-2: h2 cols [c0,c0+8), K = 2048 (64 k-tiles), waves split K
        const int bb = blk - NA;
        const int c0 = bb * 8;
        const int kbase = w * 16;
        const int colB = c0 + (cl & 7);
        const int row0 = (cl < 8) ? colB : (1024 + colB);
        const int row1 = (cl < 8) ? (2048 + colB) : (3072 + colB);
        half8 wfr[2][16];
#pragma unroll
        for (int kk = 0; kk < 16; ++kk) {
            int k0 = (kbase + kk) * 32 + quad * 8;
            wfr[0][kk] = wfrag_load(Wih2, 1024, Whh2, 1024, 1024, row0, k0);
            wfr[1][kk] = wfrag_load(Wih2, 1024, Whh2, 1024, 1024, row1, k0);
        }
        const float bi = bih2[colB] + bhh2[colB];
        const float bf = bih2[1024 + colB] + bhh2[1024 + colB];
        const float bg = bih2[2048 + colB] + bhh2[2048 + colB];
        const float bo = bih2[3072 + colB] + bhh2[3072 + colB];
        float cst[2][4];
#pragma unroll
        for (int mi = 0; mi < 2; ++mi)
#pragma unroll
            for (int r = 0; r < 4; ++r) cst[mi][r] = 0.0f;
        const int woffbase = (c0 >> 5) * 8192 + ((c0 >> 3) & 3) * 2048 + (cl & 7) * 2;
        const bool lolane = (cl & 8) == 0;

        for (int t = 0; t < TSTEPS; ++t) {
            waitB(fA, fB, fC, t);

            const char* h1c = H1 + ((t & 1) ? H1_PHASE : 0);
            const char* h2r = H2 + (((t & 1) ^ 1) ? H1_PHASE : 0);
            char*       h2w = H2 + ((t & 1) ? H1_PHASE : 0);
            const char* kb[16];
#pragma unroll
            for (int kk = 0; kk < 16; ++kk) {
                int ktg = kbase + kk;
                kb[kk] = (ktg < 32) ? (h1c + ktg * 8192) : (h2r + (ktg - 32) * 8192);
            }
            float4_ acc[8][2];
#pragma unroll
            for (int mt = 0; mt < 8; ++mt) {
                acc[mt][0] = (float4_){0.f, 0.f, 0.f, 0.f};
                acc[mt][1] = (float4_){0.f, 0.f, 0.f, 0.f};
            }
            // depth-3 fragment ring, partial vmcnt waits:
            // at iter mt: issued = 48 + 16*min(mt,5); needed = 16*(mt+1)
            // wait N: mt<=5 -> 32, mt==6 -> 16, mt==7 -> 0
            half8 af[3][16];
#pragma unroll
            for (int p = 0; p < 3; ++p)
#pragma unroll
                for (int kk = 0; kk < 16; ++kk)
                    af[p][kk] = ldg_sc1_16(kb[kk] + laneoff + p * 256);
#pragma unroll
            for (int mt = 0; mt < 8; ++mt) {
                const int s = mt % 3;
                if (mt < 6)       { VMW16(32, af[s]); }
                else if (mt == 6) { VMW16(16, af[s]); }
                else              { VMW16(0,  af[s]); }
#pragma unroll
                for (int kk = 0; kk < 16; ++kk) {
                    acc[mt][0] = __builtin_amdgcn_mfma_f32_16x16x32_f16(af[s][kk], wfr[0][kk], acc[mt][0], 0, 0, 0);
                    acc[mt][1] = __builtin_amdgcn_mfma_f32_16x16x32_f16(af[s][kk], wfr[1][kk], acc[mt][1], 0, 0, 0);
                }
                if (mt < 5) {
#pragma unroll
                    for (int kk = 0; kk < 16; ++kk)
                        af[s][kk] = ldg_sc1_16(kb[kk] + laneoff + (mt + 3) * 256);
                }
            }
#pragma unroll
            for (int r = 0; r < 4; ++r) {
                if (w != r) {
#pragma unroll
                    for (int mi = 0; mi < 2; ++mi)
#pragma unroll
                        for (int nt = 0; nt < 2; ++nt)
                            *(float4_*)&redbuf[(((w * 2 + mi) * 2 + nt) * 64 + lane) * 4] = acc[2 * r + mi][nt];
                }
                __syncthreads();
                if (w == r) {
#pragma unroll
                    for (int wo = 0; wo < 4; ++wo) if (wo != r) {
#pragma unroll
                        for (int mi = 0; mi < 2; ++mi)
#pragma unroll
                            for (int nt = 0; nt < 2; ++nt)
                                acc[2 * r + mi][nt] += *(const float4_*)&redbuf[(((wo * 2 + mi) * 2 + nt) * 64 + lane) * 4];
                    }
                }
                __syncthreads();
            }
            float4_ mine[2][2];
#pragma unroll
            for (int r = 0; r < 4; ++r) if (w == r) {
#pragma unroll
                for (int mi = 0; mi < 2; ++mi) {
                    mine[mi][0] = acc[2 * r + mi][0];
                    mine[mi][1] = acc[2 * r + mi][1];
                }
            }
#pragma unroll
            for (int mi = 0; mi < 2; ++mi) {
#pragma unroll
                for (int r = 0; r < 4; ++r) {
                    float d0 = mine[mi][0][r], d1 = mine[mi][1][r];
                    float s0 = __shfl_xor(d0, 8, 64);
                    float s1 = __shfl_xor(d1, 8, 64);
                    float iv = (lolane ? d0 : s0) + bi;
                    float fv = (lolane ? s0 : d0) + bf;
                    float gv = (lolane ? d1 : s1) + bg;
                    float ov = (lolane ? s1 : d1) + bo;
                    float c = sigf(fv) * cst[mi][r] + sigf(iv) * tanhf(gv);
                    float h = sigf(ov) * tanhf(c);
                    cst[mi][r] = c;
                    if (lolane) {
                        int m = (2 * w + mi) * 16 + quad * 4 + r;
                        stg_coh_h(h2w + woffbase + m * 16, h);
                    }
                }
            }
            publish(fB, bb, t + 1);
        }
    } else {
        // ---------- output: batch tile cb, y = h2 @ Wout^T + bout, K = 1024
        const int cb = blk - NA - NB;
        const int kbase = w * 8;
        half8 wfr[4][8];
#pragma unroll
        for (int nt = 0; nt < 4; ++nt) {
            int row = nt * 16 + cl;
#pragma unroll
            for (int kk = 0; kk < 8; ++kk)
                wfr[nt][kk] = wfrag_load(Wout, 1024, Wout, 1024, 1 << 30, row, (kbase + kk) * 32 + quad * 8);
        }
        const float bo_ = bout[w * 16 + cl];

        for (int t = 0; t < TSTEPS; ++t) {
            waitC(fB, t);
            const char* h2c = H2 + ((t & 1) ? H1_PHASE : 0);
            float4_ acc[4];
#pragma unroll
            for (int nt = 0; nt < 4; ++nt) acc[nt] = (float4_){0.f, 0.f, 0.f, 0.f};
            half8 af[8];
#pragma unroll
            for (int kk = 0; kk < 8; ++kk)
                af[kk] = ldg_sc1_16(h2c + (kbase + kk) * 8192 + laneoff + cb * 256);
            VMWAIT8(af);
#pragma unroll
            for (int kk = 0; kk < 8; ++kk)
#pragma unroll
                for (int nt = 0; nt < 4; ++nt)
                    acc[nt] = __builtin_amdgcn_mfma_f32_16x16x32_f16(af[kk], wfr[nt][kk], acc[nt], 0, 0, 0);
#pragma unroll
            for (int r = 0; r < 4; ++r) {
                if (w != r) *(float4_*)&redbuf[(w * 64 + lane) * 4] = acc[r];
                __syncthreads();
                if (w == r) {
#pragma unroll
                    for (int wo = 0; wo < 4; ++wo) if (wo != r)
                        acc[r] += *(const float4_*)&redbuf[(wo * 64 + lane) * 4];
                }
                __syncthreads();
            }
            float4_ myy = acc[0];
#pragma unroll
            for (int r = 1; r < 4; ++r) if (w == r) myy = acc[r];
#pragma unroll
            for (int r = 0; r < 4; ++r) {
                int m = cb * 16 + quad * 4 + r;
                out[(size_t)m * 32768 + (size_t)t * 64 + (w * 16 + cl)] = myy[r] + bo_;
            }
            publish(fC, cb, t + 1);
        }
    }
}

extern "C" void kernel_launch(void* const* d_in, const int* in_sizes, int n_in,
                              void* d_out, int out_size, void* d_ws, size_t ws_size,
                              hipStream_t stream) {
    const float* inp  = (const float*)d_in[0];
    const float* Wih1 = (const float*)d_in[1];
    const float* Whh1 = (const float*)d_in[2];
    const float* bih1 = (const float*)d_in[3];
    const float* bhh1 = (const float*)d_in[4];
    const float* Wih2 = (const float*)d_in[5];
    const float* Whh2 = (const float*)d_in[6];
    const float* bih2 = (const float*)d_in[7];
    const float* bhh2 = (const float*)d_in[8];
    const float* Wout = (const float*)d_in[9];
    const float* bout = (const float*)d_in[10];
    char* ws = (char*)d_ws;

    hipMemsetAsync(d_ws, 0, ZERO_BYTES, stream);
    prep_x<<<TSTEPS, 256, 0, stream>>>(inp, ws);
    lstm_persistent<<<NA + NB + NC, 256, 0, stream>>>(Wih1, Whh1, bih1, bhh1,
                                                      Wih2, Whh2, bih2, bhh2,
                                                      Wout, bout, ws, (float*)d_out);
}